// Round 1
// baseline (128.238 us; speedup 1.0000x reference)
//
#include <hip/hip_runtime.h>

#define B_ROWS 8192
#define IN_DIM 2048
#define D_DIM  1024
#define C_CLS  1000
#define C_PAD  1024

typedef __attribute__((ext_vector_type(8))) short   bf16x8;
typedef __attribute__((ext_vector_type(4))) float   f32x4;

__device__ __forceinline__ float b2f(unsigned short s) {
    unsigned int u = ((unsigned int)s) << 16;
    return __builtin_bit_cast(float, u);
}
__device__ __forceinline__ unsigned short f2b(float f) {
    unsigned int u = __builtin_bit_cast(unsigned int, f);
    u = u + 0x7fffu + ((u >> 16) & 1u);   // RNE
    return (unsigned short)(u >> 16);
}

__device__ __forceinline__ void g2lds16(const void* g, void* l) {
    __builtin_amdgcn_global_load_lds(
        (const __attribute__((address_space(1))) unsigned int*)g,
        (__attribute__((address_space(3))) unsigned int*)l,
        16, 0, 0);
}

// ---------------- W transpose + convert: W[2048][1024] f32 -> Wt[1024][2048] bf16
__global__ __launch_bounds__(256) void k_wt(const float* __restrict__ W,
                                            unsigned short* __restrict__ Wt) {
    __shared__ float t[32][33];
    const int tid = threadIdx.x;
    const int tx = tid & 31, ty = tid >> 5;           // 32 x 8
    const int kb = (blockIdx.x & 63) * 32;            // along K (2048/32=64)
    const int nb = (blockIdx.x >> 6) * 32;            // along N (1024/32=32)
#pragma unroll
    for (int j = 0; j < 4; ++j)
        t[ty + 8 * j][tx] = W[(size_t)(kb + ty + 8 * j) * D_DIM + nb + tx];
    __syncthreads();
#pragma unroll
    for (int j = 0; j < 4; ++j)
        Wt[(size_t)(nb + ty + 8 * j) * IN_DIM + kb + tx] = f2b(t[tx][ty + 8 * j]);
}

// ---------------- prototypes convert + p2; rows >= 1000 zero-filled
__global__ __launch_bounds__(256) void k_proto(const float* __restrict__ P,
                                               unsigned short* __restrict__ Pb,
                                               float* __restrict__ p2) {
    const int c = blockIdx.x;          // 0..1023
    const int tid = threadIdx.x;
    float s = 0.f;
    if (c < C_CLS) {
        float4 v = *((const float4*)(P + (size_t)c * D_DIM) + tid);
        s = v.x * v.x + v.y * v.y + v.z * v.z + v.w * v.w;
        ushort4 h; h.x = f2b(v.x); h.y = f2b(v.y); h.z = f2b(v.z); h.w = f2b(v.w);
        *((ushort4*)(Pb + (size_t)c * D_DIM) + tid) = h;
    } else {
        ushort4 h; h.x = 0; h.y = 0; h.z = 0; h.w = 0;
        *((ushort4*)(Pb + (size_t)c * D_DIM) + tid) = h;
    }
#pragma unroll
    for (int o = 32; o > 0; o >>= 1) s += __shfl_down(s, o);
    __shared__ float red[4];
    if ((tid & 63) == 0) red[tid >> 6] = s;
    __syncthreads();
    if (tid == 0) p2[c] = red[0] + red[1] + red[2] + red[3];
}

// ---------------- z2 row sum-of-squares from Z bf16
__global__ __launch_bounds__(256) void k_z2(const unsigned short* __restrict__ Zb,
                                            float* __restrict__ z2) {
    const int r = blockIdx.x, tid = threadIdx.x;
    ushort4 v = *((const ushort4*)(Zb + (size_t)r * D_DIM) + tid);
    float a = b2f(v.x), b = b2f(v.y), c = b2f(v.z), d = b2f(v.w);
    float s = a * a + b * b + c * c + d * d;
#pragma unroll
    for (int o = 32; o > 0; o >>= 1) s += __shfl_down(s, o);
    __shared__ float red[4];
    if ((tid & 63) == 0) red[tid >> 6] = s;
    __syncthreads();
    if (tid == 0) z2[r] = red[0] + red[1] + red[2] + red[3];
}

// ---------------- GEMM, 128x128 tile, BK=64, 4 waves (2x2), 16x16x32 bf16 MFMA
// MODE 0: Z = x @ Wt^T + b   (A = f32 x, reg-staged+converted; writes Zb bf16)
// MODE 1: out = (2*(Zb @ Pb^T) - z2 - p2)/1024   (both operands async-staged)
template <int MODE>
__global__ __launch_bounds__(256) void k_gemm(const float* __restrict__ Af,
                                              const unsigned short* __restrict__ Ab,
                                              const unsigned short* __restrict__ Bt,
                                              const float* __restrict__ bias,
                                              const float* __restrict__ z2,
                                              const float* __restrict__ p2,
                                              unsigned short* __restrict__ Zout,
                                              float* __restrict__ Out) {
    constexpr int K = (MODE == 0) ? IN_DIM : D_DIM;
    const int tid  = threadIdx.x;
    const int wave = tid >> 6, lane = tid & 63;
    const int lo = lane & 15, hi = lane >> 4;
    const int wm = wave >> 1, wn = wave & 1;

    const int bn = blockIdx.x & 7;    // N: 1024/128 = 8
    const int bm = blockIdx.x >> 3;   // M: 8192/128 = 64
    const int rowbase = bm * 128;
    const int colbase = bn * 128;

    __shared__ unsigned short lA[128 * 64];   // [row][k] bf16, 128B rows, XOR-swizzled
    __shared__ unsigned short lB[128 * 64];   // [col][k] bf16 (B^T layout)

    f32x4 acc[4][4];
#pragma unroll
    for (int m = 0; m < 4; ++m)
#pragma unroll
        for (int n = 0; n < 4; ++n) acc[m][n] = (f32x4){0.f, 0.f, 0.f, 0.f};

    // async staging geometry: segment = 1KB = 8 rows; lane l -> row l/8, chunk l%8
    const int srow   = lane >> 3;
    const int schunk = lane & 7;
    const int gchunk = schunk ^ (srow & 7);       // inverse-swizzled global source
    // reg-stage geometry (MODE 0 A): thread t -> row t/8 (+32/iter), chunk t%8
    const int arow   = tid >> 3;
    const int achunk = tid & 7;

    for (int kt = 0; kt < K / 64; ++kt) {
        __syncthreads();   // previous tile fully consumed
        // ---- stage B (always async, bf16 in ws)
#pragma unroll
        for (int i = 0; i < 4; ++i) {
            const int s = i * 4 + wave;
            const unsigned short* g =
                Bt + (size_t)(colbase + s * 8 + srow) * K + kt * 64 + gchunk * 8;
            g2lds16(g, (void*)((char*)lB + s * 1024));
        }
        // ---- stage A
        if constexpr (MODE == 1) {
#pragma unroll
            for (int i = 0; i < 4; ++i) {
                const int s = i * 4 + wave;
                const unsigned short* g =
                    Ab + (size_t)(rowbase + s * 8 + srow) * K + kt * 64 + gchunk * 8;
                g2lds16(g, (void*)((char*)lA + s * 1024));
            }
        } else {
#pragma unroll
            for (int i = 0; i < 4; ++i) {
                const int r = i * 32 + arow;   // 0..127
                const float4* gp =
                    (const float4*)(Af + (size_t)(rowbase + r) * K + kt * 64 + achunk * 8);
                float4 v0 = gp[0], v1 = gp[1];
                bf16x8 hv;
                hv[0] = (short)f2b(v0.x); hv[1] = (short)f2b(v0.y);
                hv[2] = (short)f2b(v0.z); hv[3] = (short)f2b(v0.w);
                hv[4] = (short)f2b(v1.x); hv[5] = (short)f2b(v1.y);
                hv[6] = (short)f2b(v1.z); hv[7] = (short)f2b(v1.w);
                unsigned addr = (unsigned)(r * 128 + achunk * 16) ^ (unsigned)((r & 7) << 4);
                *(bf16x8*)((char*)lA + addr) = hv;
            }
        }
        __syncthreads();   // drains vmcnt (global_load_lds) + lgkmcnt (ds_write)

        // ---- compute: 2 sub-steps of K=32
#pragma unroll
        for (int ks = 0; ks < 2; ++ks) {
            bf16x8 af[4], bfr[4];
#pragma unroll
            for (int m = 0; m < 4; ++m) {
                const int row = wm * 64 + m * 16 + lo;
                unsigned addr = (unsigned)(row * 128 + ks * 64 + hi * 16)
                              ^ (unsigned)((lo & 7) << 4);
                af[m] = *(const bf16x8*)((const char*)lA + addr);
            }
#pragma unroll
            for (int n = 0; n < 4; ++n) {
                const int row = wn * 64 + n * 16 + lo;
                unsigned addr = (unsigned)(row * 128 + ks * 64 + hi * 16)
                              ^ (unsigned)((lo & 7) << 4);
                bfr[n] = *(const bf16x8*)((const char*)lB + addr);
            }
#pragma unroll
            for (int m = 0; m < 4; ++m)
#pragma unroll
                for (int n = 0; n < 4; ++n)
                    acc[m][n] = __builtin_amdgcn_mfma_f32_16x16x32_bf16(
                        af[m], bfr[n], acc[m][n], 0, 0, 0);
        }
    }

    // ---- epilogue  (C/D layout: col = lane&15, row = (lane>>4)*4 + reg)
    if constexpr (MODE == 0) {
        float bv[4];
#pragma unroll
        for (int n = 0; n < 4; ++n) bv[n] = bias[colbase + wn * 64 + n * 16 + lo];
#pragma unroll
        for (int m = 0; m < 4; ++m)
#pragma unroll
            for (int r = 0; r < 4; ++r) {
                const int rg = rowbase + wm * 64 + m * 16 + hi * 4 + r;
#pragma unroll
                for (int n = 0; n < 4; ++n) {
                    const int cg = colbase + wn * 64 + n * 16 + lo;
                    Zout[(size_t)rg * D_DIM + cg] = f2b(acc[m][n][r] + bv[n]);
                }
            }
    } else {
        float p2v[4];
#pragma unroll
        for (int n = 0; n < 4; ++n) p2v[n] = p2[colbase + wn * 64 + n * 16 + lo];
#pragma unroll
        for (int m = 0; m < 4; ++m)
#pragma unroll
            for (int r = 0; r < 4; ++r) {
                const int rg = rowbase + wm * 64 + m * 16 + hi * 4 + r;
                const float zv = z2[rg];
#pragma unroll
                for (int n = 0; n < 4; ++n) {
                    const int cg = colbase + wn * 64 + n * 16 + lo;
                    if (cg < C_CLS)
                        Out[(size_t)rg * C_CLS + cg] =
                            (2.f * acc[m][n][r] - zv - p2v[n]) * (1.f / 1024.f);
                }
            }
    }
}

extern "C" void kernel_launch(void* const* d_in, const int* in_sizes, int n_in,
                              void* d_out, int out_size, void* d_ws, size_t ws_size,
                              hipStream_t stream) {
    const float* x = (const float*)d_in[0];   // [8192, 2048]
    const float* W = (const float*)d_in[1];   // [2048, 1024]
    const float* b = (const float*)d_in[2];   // [1024]
    const float* P = (const float*)d_in[3];   // [1000, 1024]
    float* out = (float*)d_out;               // [8192, 1000]

    char* ws = (char*)d_ws;
    unsigned short* Wt = (unsigned short*)(ws);                       //  4 MB
    unsigned short* Pb = (unsigned short*)(ws + (4  << 20));          //  2 MB
    unsigned short* Zb = (unsigned short*)(ws + (6  << 20));          // 16 MB
    float*          z2 = (float*)(ws + (22 << 20));                   // 32 KB
    float*          p2 = (float*)(ws + (22 << 20) + (64 << 10));      //  4 KB

    k_wt<<<dim3(2048), dim3(256), 0, stream>>>(W, Wt);
    k_proto<<<dim3(1024), dim3(256), 0, stream>>>(P, Pb, p2);
    k_gemm<0><<<dim3(512), dim3(256), 0, stream>>>(x, nullptr, Wt, b,
                                                   nullptr, nullptr, Zb, nullptr);
    k_z2<<<dim3(8192), dim3(256), 0, stream>>>(Zb, z2);
    k_gemm<1><<<dim3(512), dim3(256), 0, stream>>>(nullptr, Zb, Pb, nullptr,
                                                   z2, p2, nullptr, out);
}

// Round 2
// 102.137 us; speedup vs baseline: 1.2555x; 1.2555x over previous
//
#include <hip/hip_runtime.h>

#define B_ROWS 8192
#define IN_DIM 2048
#define D_DIM  1024
#define C_CLS  1000
#define C_PAD  1024

typedef __attribute__((ext_vector_type(8))) short   bf16x8;
typedef __attribute__((ext_vector_type(4))) float   f32x4;

__device__ __forceinline__ float b2f(unsigned short s) {
    unsigned int u = ((unsigned int)s) << 16;
    return __builtin_bit_cast(float, u);
}
__device__ __forceinline__ unsigned short f2b(float f) {
    unsigned int u = __builtin_bit_cast(unsigned int, f);
    u = u + 0x7fffu + ((u >> 16) & 1u);   // RNE
    return (unsigned short)(u >> 16);
}

__device__ __forceinline__ void g2lds16(const void* g, void* l) {
    __builtin_amdgcn_global_load_lds(
        (const __attribute__((address_space(1))) unsigned int*)g,
        (__attribute__((address_space(3))) unsigned int*)l,
        16, 0, 0);
}

// ---------------- x f32 -> bf16 (8 elems/thread)
__global__ __launch_bounds__(256) void k_xb(const float* __restrict__ x,
                                            unsigned short* __restrict__ xb) {
    const size_t i = ((size_t)blockIdx.x * 256 + threadIdx.x) * 8;
    float4 v0 = *(const float4*)(x + i);
    float4 v1 = *(const float4*)(x + i + 4);
    bf16x8 h;
    h[0] = (short)f2b(v0.x); h[1] = (short)f2b(v0.y);
    h[2] = (short)f2b(v0.z); h[3] = (short)f2b(v0.w);
    h[4] = (short)f2b(v1.x); h[5] = (short)f2b(v1.y);
    h[6] = (short)f2b(v1.z); h[7] = (short)f2b(v1.w);
    *(bf16x8*)(xb + i) = h;
}

// ---------------- W transpose + convert: W[2048][1024] f32 -> Wt[1024][2048] bf16
__global__ __launch_bounds__(256) void k_wt(const float* __restrict__ W,
                                            unsigned short* __restrict__ Wt) {
    __shared__ float t[32][33];
    const int tid = threadIdx.x;
    const int tx = tid & 31, ty = tid >> 5;           // 32 x 8
    const int kb = (blockIdx.x & 63) * 32;            // along K (2048/32=64)
    const int nb = (blockIdx.x >> 6) * 32;            // along N (1024/32=32)
#pragma unroll
    for (int j = 0; j < 4; ++j)
        t[ty + 8 * j][tx] = W[(size_t)(kb + ty + 8 * j) * D_DIM + nb + tx];
    __syncthreads();
#pragma unroll
    for (int j = 0; j < 4; ++j)
        Wt[(size_t)(nb + ty + 8 * j) * IN_DIM + kb + tx] = f2b(t[tx][ty + 8 * j]);
}

// ---------------- prototypes convert + p2; rows >= 1000 zero-filled
__global__ __launch_bounds__(256) void k_proto(const float* __restrict__ P,
                                               unsigned short* __restrict__ Pb,
                                               float* __restrict__ p2) {
    const int c = blockIdx.x;          // 0..1023
    const int tid = threadIdx.x;
    float s = 0.f;
    if (c < C_CLS) {
        float4 v = *((const float4*)(P + (size_t)c * D_DIM) + tid);
        s = v.x * v.x + v.y * v.y + v.z * v.z + v.w * v.w;
        ushort4 h; h.x = f2b(v.x); h.y = f2b(v.y); h.z = f2b(v.z); h.w = f2b(v.w);
        *((ushort4*)(Pb + (size_t)c * D_DIM) + tid) = h;
    } else {
        ushort4 h; h.x = 0; h.y = 0; h.z = 0; h.w = 0;
        *((ushort4*)(Pb + (size_t)c * D_DIM) + tid) = h;
    }
#pragma unroll
    for (int o = 32; o > 0; o >>= 1) s += __shfl_down(s, o);
    __shared__ float red[4];
    if ((tid & 63) == 0) red[tid >> 6] = s;
    __syncthreads();
    if (tid == 0) p2[c] = red[0] + red[1] + red[2] + red[3];
}

// ---------------- z2 row sum-of-squares from Z bf16
__global__ __launch_bounds__(256) void k_z2(const unsigned short* __restrict__ Zb,
                                            float* __restrict__ z2) {
    const int r = blockIdx.x, tid = threadIdx.x;
    ushort4 v = *((const ushort4*)(Zb + (size_t)r * D_DIM) + tid);
    float a = b2f(v.x), b = b2f(v.y), c = b2f(v.z), d = b2f(v.w);
    float s = a * a + b * b + c * c + d * d;
#pragma unroll
    for (int o = 32; o > 0; o >>= 1) s += __shfl_down(s, o);
    __shared__ float red[4];
    if ((tid & 63) == 0) red[tid >> 6] = s;
    __syncthreads();
    if (tid == 0) z2[r] = red[0] + red[1] + red[2] + red[3];
}

// ---------------- GEMM, 128x128 tile, BK=64, 4 waves (2x2), 16x16x32 bf16 MFMA
// Double-buffered LDS, one barrier per K-tile, XCD-swizzled grid.
// MODE 0: Z = A @ Wt^T + b   -> Zb bf16.  ASYNC_A: A already bf16 (xb);
//         else A = f32 x, reg-staged (T14 split: load early, write late).
// MODE 1: out = (2*(Zb @ Pb^T) - z2 - p2)/1024
template <int MODE, bool ASYNC_A>
__global__ __launch_bounds__(256) void k_gemm(const float* __restrict__ Af,
                                              const unsigned short* __restrict__ Ab,
                                              const unsigned short* __restrict__ Bt,
                                              const float* __restrict__ bias,
                                              const float* __restrict__ z2,
                                              const float* __restrict__ p2,
                                              unsigned short* __restrict__ Zout,
                                              float* __restrict__ Out) {
    constexpr int K  = (MODE == 0) ? IN_DIM : D_DIM;
    constexpr int NT = K / 64;
    const int tid  = threadIdx.x;
    const int wave = tid >> 6, lane = tid & 63;
    const int lo = lane & 15, hi = lane >> 4;
    const int wm = wave >> 1, wn = wave & 1;

    // XCD-aware bijective swizzle (nwg = 512, 512 % 8 == 0)
    const int nwg = gridDim.x;
    const int swz = (blockIdx.x & 7) * (nwg >> 3) + (blockIdx.x >> 3);
    const int bn = swz & 7;    // N: 1024/128 = 8
    const int bm = swz >> 3;   // M: 8192/128 = 64
    const int rowbase = bm * 128;
    const int colbase = bn * 128;

    __shared__ unsigned short lA[2][128 * 64];  // [row][k] bf16, XOR-swizzled
    __shared__ unsigned short lB[2][128 * 64];  // [col][k] bf16 (B^T layout)

    f32x4 acc[4][4];
#pragma unroll
    for (int m = 0; m < 4; ++m)
#pragma unroll
        for (int n = 0; n < 4; ++n) acc[m][n] = (f32x4){0.f, 0.f, 0.f, 0.f};

    // async staging geometry: segment = 1KB = 8 rows; lane l -> row l/8, chunk l%8
    const int srow   = lane >> 3;
    const int schunk = lane & 7;
    const int gchunk = schunk ^ (srow & 7);       // inverse-swizzled global source
    // reg-stage geometry (fallback A): thread t -> row t/8 (+32/iter), chunk t%8
    const int arow   = tid >> 3;
    const int achunk = tid & 7;

    float4 pv0[4], pv1[4];   // T14 in-flight regs (fallback path)

    auto STAGE = [&](int buf, int kt) {
#pragma unroll
        for (int i = 0; i < 4; ++i) {
            const int s = i * 4 + wave;
            g2lds16(Bt + (size_t)(colbase + s * 8 + srow) * K + kt * 64 + gchunk * 8,
                    (char*)lB[buf] + s * 1024);
        }
        if constexpr (ASYNC_A) {
#pragma unroll
            for (int i = 0; i < 4; ++i) {
                const int s = i * 4 + wave;
                g2lds16(Ab + (size_t)(rowbase + s * 8 + srow) * K + kt * 64 + gchunk * 8,
                        (char*)lA[buf] + s * 1024);
            }
        }
    };
    auto LOADA = [&](int kt) {
#pragma unroll
        for (int i = 0; i < 4; ++i) {
            const int r = i * 32 + arow;
            const float4* gp =
                (const float4*)(Af + (size_t)(rowbase + r) * K + kt * 64 + achunk * 8);
            pv0[i] = gp[0]; pv1[i] = gp[1];
        }
    };
    auto WRITEA = [&](int buf) {
#pragma unroll
        for (int i = 0; i < 4; ++i) {
            const int r = i * 32 + arow;
            bf16x8 hv;
            hv[0] = (short)f2b(pv0[i].x); hv[1] = (short)f2b(pv0[i].y);
            hv[2] = (short)f2b(pv0[i].z); hv[3] = (short)f2b(pv0[i].w);
            hv[4] = (short)f2b(pv1[i].x); hv[5] = (short)f2b(pv1[i].y);
            hv[6] = (short)f2b(pv1[i].z); hv[7] = (short)f2b(pv1[i].w);
            unsigned addr = (unsigned)(r * 128 + achunk * 16) ^ (unsigned)((r & 7) << 4);
            *(bf16x8*)((char*)lA[buf] + addr) = hv;
        }
    };

    // prologue: fill buffer 0
    STAGE(0, 0);
    if constexpr (!ASYNC_A) { LOADA(0); WRITEA(0); }
    __syncthreads();

    int cur = 0;
    for (int kt = 0; kt < NT; ++kt) {
        const bool hasNext = (kt + 1 < NT);
        if (hasNext) {
            STAGE(cur ^ 1, kt + 1);               // async loads in flight over compute
            if constexpr (!ASYNC_A) LOADA(kt + 1); // global->reg issue (T14 early)
        }

        // ---- compute from buf[cur]: 2 sub-steps of K=32
#pragma unroll
        for (int ks = 0; ks < 2; ++ks) {
            bf16x8 af[4], bfr[4];
#pragma unroll
            for (int m = 0; m < 4; ++m) {
                const int row = wm * 64 + m * 16 + lo;
                unsigned addr = (unsigned)(row * 128 + ks * 64 + hi * 16)
                              ^ (unsigned)((lo & 7) << 4);
                af[m] = *(const bf16x8*)((const char*)lA[cur] + addr);
            }
#pragma unroll
            for (int n = 0; n < 4; ++n) {
                const int row = wn * 64 + n * 16 + lo;
                unsigned addr = (unsigned)(row * 128 + ks * 64 + hi * 16)
                              ^ (unsigned)((lo & 7) << 4);
                bfr[n] = *(const bf16x8*)((const char*)lB[cur] + addr);
            }
            __builtin_amdgcn_s_setprio(1);
#pragma unroll
            for (int m = 0; m < 4; ++m)
#pragma unroll
                for (int n = 0; n < 4; ++n)
                    acc[m][n] = __builtin_amdgcn_mfma_f32_16x16x32_bf16(
                        af[m], bfr[n], acc[m][n], 0, 0, 0);
            __builtin_amdgcn_s_setprio(0);
        }

        if (hasNext) {
            if constexpr (!ASYNC_A) WRITEA(cur ^ 1);  // T14 late write (vmcnt waits here)
        }
        __syncthreads();   // drains vmcnt (prefetch) + lgkmcnt; one barrier per K-tile
        cur ^= 1;
    }

    // ---- epilogue  (C/D layout: col = lane&15, row = (lane>>4)*4 + reg)
    if constexpr (MODE == 0) {
        float bv[4];
#pragma unroll
        for (int n = 0; n < 4; ++n) bv[n] = bias[colbase + wn * 64 + n * 16 + lo];
#pragma unroll
        for (int m = 0; m < 4; ++m)
#pragma unroll
            for (int r = 0; r < 4; ++r) {
                const int rg = rowbase + wm * 64 + m * 16 + hi * 4 + r;
#pragma unroll
                for (int n = 0; n < 4; ++n) {
                    const int cg = colbase + wn * 64 + n * 16 + lo;
                    Zout[(size_t)rg * D_DIM + cg] = f2b(acc[m][n][r] + bv[n]);
                }
            }
    } else {
        float p2v[4];
#pragma unroll
        for (int n = 0; n < 4; ++n) p2v[n] = p2[colbase + wn * 64 + n * 16 + lo];
#pragma unroll
        for (int m = 0; m < 4; ++m)
#pragma unroll
            for (int r = 0; r < 4; ++r) {
                const int rg = rowbase + wm * 64 + m * 16 + hi * 4 + r;
                const float zv = z2[rg];
#pragma unroll
                for (int n = 0; n < 4; ++n) {
                    const int cg = colbase + wn * 64 + n * 16 + lo;
                    if (cg < C_CLS)
                        Out[(size_t)rg * C_CLS + cg] =
                            (2.f * acc[m][n][r] - zv - p2v[n]) * (1.f / 1024.f);
                }
            }
    }
}

extern "C" void kernel_launch(void* const* d_in, const int* in_sizes, int n_in,
                              void* d_out, int out_size, void* d_ws, size_t ws_size,
                              hipStream_t stream) {
    const float* x = (const float*)d_in[0];   // [8192, 2048]
    const float* W = (const float*)d_in[1];   // [2048, 1024]
    const float* b = (const float*)d_in[2];   // [1024]
    const float* P = (const float*)d_in[3];   // [1000, 1024]
    float* out = (float*)d_out;               // [8192, 1000]

    char* ws = (char*)d_ws;
    unsigned short* Wt = (unsigned short*)(ws);                       //  4 MB
    unsigned short* Pb = (unsigned short*)(ws + (4  << 20));          //  2 MB
    unsigned short* Zb = (unsigned short*)(ws + (6  << 20));          // 16 MB
    float*          z2 = (float*)(ws + (22 << 20));                   // 32 KB
    float*          p2 = (float*)(ws + (22 << 20) + (64 << 10));      //  4 KB
    unsigned short* xb = (unsigned short*)(ws + (23 << 20));          // 32 MB (optional)

    const bool big_ws = ws_size >= ((23ull << 20) + (32ull << 20));

    k_wt<<<dim3(2048), dim3(256), 0, stream>>>(W, Wt);
    k_proto<<<dim3(1024), dim3(256), 0, stream>>>(P, Pb, p2);
    if (big_ws) {
        k_xb<<<dim3(8192), dim3(256), 0, stream>>>(x, xb);
        k_gemm<0, true><<<dim3(512), dim3(256), 0, stream>>>(
            nullptr, xb, Wt, b, nullptr, nullptr, Zb, nullptr);
    } else {
        k_gemm<0, false><<<dim3(512), dim3(256), 0, stream>>>(
            x, nullptr, Wt, b, nullptr, nullptr, Zb, nullptr);
    }
    k_z2<<<dim3(8192), dim3(256), 0, stream>>>(Zb, z2);
    k_gemm<1, true><<<dim3(512), dim3(256), 0, stream>>>(
        nullptr, Zb, Pb, nullptr, z2, p2, nullptr, out);
}

// Round 3
// 88.531 us; speedup vs baseline: 1.4485x; 1.1537x over previous
//
#include <hip/hip_runtime.h>

#define B_ROWS 8192
#define IN_DIM 2048
#define D_DIM  1024
#define C_CLS  1000

typedef __attribute__((ext_vector_type(8))) short   bf16x8;
typedef __attribute__((ext_vector_type(4))) float   f32x4;

__device__ __forceinline__ float b2f(unsigned short s) {
    unsigned int u = ((unsigned int)s) << 16;
    return __builtin_bit_cast(float, u);
}
__device__ __forceinline__ unsigned short f2b(float f) {
    unsigned int u = __builtin_bit_cast(unsigned int, f);
    u = u + 0x7fffu + ((u >> 16) & 1u);   // RNE
    return (unsigned short)(u >> 16);
}

__device__ __forceinline__ void g2lds16(const void* g, void* l) {
    __builtin_amdgcn_global_load_lds(
        (const __attribute__((address_space(1))) unsigned int*)g,
        (__attribute__((address_space(3))) unsigned int*)l,
        16, 0, 0);
}

// ---------------- x f32 -> bf16 (8 elems/thread)
__global__ __launch_bounds__(256) void k_xb(const float* __restrict__ x,
                                            unsigned short* __restrict__ xb) {
    const size_t i = ((size_t)blockIdx.x * 256 + threadIdx.x) * 8;
    float4 v0 = *(const float4*)(x + i);
    float4 v1 = *(const float4*)(x + i + 4);
    bf16x8 h;
    h[0] = (short)f2b(v0.x); h[1] = (short)f2b(v0.y);
    h[2] = (short)f2b(v0.z); h[3] = (short)f2b(v0.w);
    h[4] = (short)f2b(v1.x); h[5] = (short)f2b(v1.y);
    h[6] = (short)f2b(v1.z); h[7] = (short)f2b(v1.w);
    *(bf16x8*)(xb + i) = h;
}

// ---------------- W transpose + convert: W[2048][1024] f32 -> Wt[1024][2048] bf16
__global__ __launch_bounds__(256) void k_wt(const float* __restrict__ W,
                                            unsigned short* __restrict__ Wt) {
    __shared__ float t[32][33];
    const int tid = threadIdx.x;
    const int tx = tid & 31, ty = tid >> 5;           // 32 x 8
    const int kb = (blockIdx.x & 63) * 32;            // along K (2048/32=64)
    const int nb = (blockIdx.x >> 6) * 32;            // along N (1024/32=32)
#pragma unroll
    for (int j = 0; j < 4; ++j)
        t[ty + 8 * j][tx] = W[(size_t)(kb + ty + 8 * j) * D_DIM + nb + tx];
    __syncthreads();
#pragma unroll
    for (int j = 0; j < 4; ++j)
        Wt[(size_t)(nb + ty + 8 * j) * IN_DIM + kb + tx] = f2b(t[tx][ty + 8 * j]);
}

// ---------------- prototypes convert + p2; rows >= 1000 zero-filled
__global__ __launch_bounds__(256) void k_proto(const float* __restrict__ P,
                                               unsigned short* __restrict__ Pb,
                                               float* __restrict__ p2) {
    const int c = blockIdx.x;          // 0..1023
    const int tid = threadIdx.x;
    float s = 0.f;
    if (c < C_CLS) {
        float4 v = *((const float4*)(P + (size_t)c * D_DIM) + tid);
        s = v.x * v.x + v.y * v.y + v.z * v.z + v.w * v.w;
        ushort4 h; h.x = f2b(v.x); h.y = f2b(v.y); h.z = f2b(v.z); h.w = f2b(v.w);
        *((ushort4*)(Pb + (size_t)c * D_DIM) + tid) = h;
    } else {
        ushort4 h; h.x = 0; h.y = 0; h.z = 0; h.w = 0;
        *((ushort4*)(Pb + (size_t)c * D_DIM) + tid) = h;
    }
#pragma unroll
    for (int o = 32; o > 0; o >>= 1) s += __shfl_down(s, o);
    __shared__ float red[4];
    if ((tid & 63) == 0) red[tid >> 6] = s;
    __syncthreads();
    if (tid == 0) p2[c] = red[0] + red[1] + red[2] + red[3];
}

// ---------------- z2 partial reduce: z2p[16][8192] -> z2[8192]
__global__ __launch_bounds__(256) void k_z2r(const float* __restrict__ z2p,
                                             float* __restrict__ z2) {
    const int r = blockIdx.x * 256 + threadIdx.x;
    float s = 0.f;
#pragma unroll
    for (int j = 0; j < 16; ++j) s += z2p[j * B_ROWS + r];
    z2[r] = s;
}

// ---------------- deep-pipelined GEMM: tile 256x128, BK=64, 512 thr (8 waves 4Mx2N)
// 3-stage LDS (A 3x32KB + B 3x16KB = 144KB dynamic), counted vmcnt(6), raw barriers.
// MODE 0: Zb = Ab @ Bt^T + bias (bf16 out) + z2 partials
// MODE 1: Out = (2*(Ab @ Bt^T) - z2 - p2)/1024, cols masked to C_CLS
template <int MODE>
__global__ __launch_bounds__(512, 2) void k_gemm8(
    const unsigned short* __restrict__ Ab,   // [M][K] bf16
    const unsigned short* __restrict__ Bt,   // [N][K] bf16
    const float* __restrict__ bias,
    const float* __restrict__ z2,
    const float* __restrict__ p2,
    unsigned short* __restrict__ Zout,
    float* __restrict__ z2p,
    float* __restrict__ Out) {
    constexpr int K  = (MODE == 0) ? IN_DIM : D_DIM;
    constexpr int NT = K / 64;
    constexpr unsigned ASZ = 256 * 64 * 2;   // 32 KB per stage
    constexpr unsigned BSZ = 128 * 64 * 2;   // 16 KB per stage
    extern __shared__ char lds[];
    char* pa0 = lds;            char* pa1 = lds + ASZ;  char* pa2 = lds + 2 * ASZ;
    char* pb0 = lds + 3 * ASZ;  char* pb1 = pb0 + BSZ;  char* pb2 = pb0 + 2 * BSZ;

    const int tid  = threadIdx.x;
    const int wave = tid >> 6, lane = tid & 63;
    const int lo = lane & 15, hi = lane >> 4;
    const int wm = wave >> 1, wn = wave & 1;   // 4M x 2N waves, 64x64 each

    // XCD-aware bijective swizzle: 256 blocks, 8 XCDs, 32 each
    const int swz = ((blockIdx.x & 7) << 5) + (blockIdx.x >> 3);
    const int bm = swz >> 3, bn = swz & 7;     // 32 x 8
    const int rowbase = bm * 256, colbase = bn * 128;

    // staging: segment = 1KB = 8 rows x 128B; lane -> row lane>>3, chunk lane&7
    // LDS dest linear; global source chunk pre-XOR'd so read-side XOR matches
    const int srow   = lane >> 3;
    const int gchunk = (lane & 7) ^ (srow & 7);

    auto STAGE_A = [&](char* dst, int kt, int i) {   // i in 0..3, 32 segs / 8 waves
        const int s = i * 8 + wave;
        g2lds16(Ab + (size_t)(rowbase + s * 8 + srow) * K + kt * 64 + gchunk * 8,
                dst + s * 1024);
    };
    auto STAGE_B = [&](char* dst, int kt, int i) {   // i in 0..1, 16 segs / 8 waves
        const int s = i * 8 + wave;
        g2lds16(Bt + (size_t)(colbase + s * 8 + srow) * K + kt * 64 + gchunk * 8,
                dst + s * 1024);
    };

    f32x4 acc[4][4];
#pragma unroll
    for (int m = 0; m < 4; ++m)
#pragma unroll
        for (int n = 0; n < 4; ++n) acc[m][n] = (f32x4){0.f, 0.f, 0.f, 0.f};

    // ---- prologue: stage tiles 0 and 1 (12 loads); wait for tile 0 (vmcnt 6)
#pragma unroll
    for (int i = 0; i < 4; ++i) STAGE_A(pa0, 0, i);
#pragma unroll
    for (int i = 0; i < 2; ++i) STAGE_B(pb0, 0, i);
#pragma unroll
    for (int i = 0; i < 4; ++i) STAGE_A(pa1, 1, i);
#pragma unroll
    for (int i = 0; i < 2; ++i) STAGE_B(pb1, 1, i);
    asm volatile("s_waitcnt vmcnt(6)" ::: "memory");
    __builtin_amdgcn_s_barrier();

    // one phase: 8 ds_read_b128 + (optional 3 prefetch issues) + barrier + 16 MFMA
    auto PHASE = [&](int ks, int stg, int kt2) {     // stg: 0 none, 1 half0, 2 half1
        bf16x8 af[4], bfr[4];
#pragma unroll
        for (int m = 0; m < 4; ++m) {
            const int row = wm * 64 + m * 16 + lo;
            unsigned addr = (unsigned)(row * 128 + ks * 64 + hi * 16)
                          ^ (unsigned)((lo & 7) << 4);
            af[m] = *(const bf16x8*)(pa0 + addr);
        }
#pragma unroll
        for (int n = 0; n < 4; ++n) {
            const int row = wn * 64 + n * 16 + lo;
            unsigned addr = (unsigned)(row * 128 + ks * 64 + hi * 16)
                          ^ (unsigned)((lo & 7) << 4);
            bfr[n] = *(const bf16x8*)(pb0 + addr);
        }
        if (stg == 1) { STAGE_A(pa2, kt2, 0); STAGE_A(pa2, kt2, 1); STAGE_B(pb2, kt2, 0); }
        if (stg == 2) { STAGE_A(pa2, kt2, 2); STAGE_A(pa2, kt2, 3); STAGE_B(pb2, kt2, 1); }
        __builtin_amdgcn_s_barrier();
        __builtin_amdgcn_s_setprio(1);
#pragma unroll
        for (int m = 0; m < 4; ++m)
#pragma unroll
            for (int n = 0; n < 4; ++n)
                acc[m][n] = __builtin_amdgcn_mfma_f32_16x16x32_bf16(
                    af[m], bfr[n], acc[m][n], 0, 0, 0);
        __builtin_amdgcn_s_setprio(0);
    };
    auto ROTATE = [&]() {
        char* t;
        t = pa0; pa0 = pa1; pa1 = pa2; pa2 = t;
        t = pb0; pb0 = pb1; pb1 = pb2; pb2 = t;
    };

    // ---- main loop: compute tile t, prefetch tile t+2, counted vmcnt(6)
    for (int t = 0; t < NT - 2; ++t) {
        PHASE(0, 1, t + 2);
        __builtin_amdgcn_s_barrier();
        PHASE(1, 2, t + 2);
        asm volatile("s_waitcnt vmcnt(6)" ::: "memory");   // tile t+1 resident
        __builtin_amdgcn_s_barrier();
        ROTATE();
    }
    // tile NT-2: nothing left to prefetch; drain remaining (tile NT-1's 6 loads)
    PHASE(0, 0, 0);
    __builtin_amdgcn_s_barrier();
    PHASE(1, 0, 0);
    asm volatile("s_waitcnt vmcnt(0)" ::: "memory");
    __builtin_amdgcn_s_barrier();
    ROTATE();
    // tile NT-1
    PHASE(0, 0, 0);
    __builtin_amdgcn_s_barrier();
    PHASE(1, 0, 0);

    // ---- epilogue (C/D: col = lane&15, row = (lane>>4)*4 + reg)
    if constexpr (MODE == 0) {
        float bv[4];
#pragma unroll
        for (int n = 0; n < 4; ++n) bv[n] = bias[colbase + wn * 64 + n * 16 + lo];
#pragma unroll
        for (int m = 0; m < 4; ++m)
#pragma unroll
            for (int r = 0; r < 4; ++r) {
                const int rg = rowbase + wm * 64 + m * 16 + hi * 4 + r;
                float s = 0.f;
#pragma unroll
                for (int n = 0; n < 4; ++n) {
                    const float zf = acc[m][n][r] + bv[n];
                    Zout[(size_t)rg * D_DIM + colbase + wn * 64 + n * 16 + lo] = f2b(zf);
                    s += zf * zf;
                }
                s += __shfl_xor(s, 1); s += __shfl_xor(s, 2);
                s += __shfl_xor(s, 4); s += __shfl_xor(s, 8);
                if (lo == 0) z2p[(size_t)(bn * 2 + wn) * B_ROWS + rg] = s;
            }
    } else {
        float p2v[4];
#pragma unroll
        for (int n = 0; n < 4; ++n) p2v[n] = p2[colbase + wn * 64 + n * 16 + lo];
#pragma unroll
        for (int m = 0; m < 4; ++m)
#pragma unroll
            for (int r = 0; r < 4; ++r) {
                const int rg = rowbase + wm * 64 + m * 16 + hi * 4 + r;
                const float zv = z2[rg];
#pragma unroll
                for (int n = 0; n < 4; ++n) {
                    const int cg = colbase + wn * 64 + n * 16 + lo;
                    if (cg < C_CLS)
                        Out[(size_t)rg * C_CLS + cg] =
                            (2.f * acc[m][n][r] - zv - p2v[n]) * (1.f / 1024.f);
                }
            }
    }
}

extern "C" void kernel_launch(void* const* d_in, const int* in_sizes, int n_in,
                              void* d_out, int out_size, void* d_ws, size_t ws_size,
                              hipStream_t stream) {
    const float* x = (const float*)d_in[0];   // [8192, 2048]
    const float* W = (const float*)d_in[1];   // [2048, 1024]
    const float* b = (const float*)d_in[2];   // [1024]
    const float* P = (const float*)d_in[3];   // [1000, 1024]
    float* out = (float*)d_out;               // [8192, 1000]

    char* ws = (char*)d_ws;
    unsigned short* Wt  = (unsigned short*)(ws);                        //  4 MB
    unsigned short* Pb  = (unsigned short*)(ws + (4  << 20));           //  2 MB
    unsigned short* Zb  = (unsigned short*)(ws + (6  << 20));           // 16 MB
    float*          z2  = (float*)(ws + (22 << 20));                    // 32 KB
    float*          p2  = (float*)(ws + (22 << 20) + (64 << 10));       //  4 KB
    float*          z2p = (float*)(ws + (22 << 20) + (128 << 10));      // 512 KB
    unsigned short* xb  = (unsigned short*)(ws + (23 << 20));           // 32 MB

    const unsigned lds_bytes = 3 * (256 * 64 * 2) + 3 * (128 * 64 * 2); // 144 KB

    k_wt<<<dim3(2048), dim3(256), 0, stream>>>(W, Wt);
    k_proto<<<dim3(1024), dim3(256), 0, stream>>>(P, Pb, p2);
    k_xb<<<dim3(8192), dim3(256), 0, stream>>>(x, xb);
    k_gemm8<0><<<dim3(256), dim3(512), lds_bytes, stream>>>(
        xb, Wt, b, nullptr, nullptr, Zb, z2p, nullptr);
    k_z2r<<<dim3(32), dim3(256), 0, stream>>>(z2p, z2);
    k_gemm8<1><<<dim3(256), dim3(512), lds_bytes, stream>>>(
        Zb, Pb, nullptr, z2, p2, nullptr, nullptr, out);
}